// Round 13
// baseline (322.827 us; speedup 1.0000x reference)
//
#include <hip/hip_runtime.h>

typedef unsigned short u16;
typedef unsigned int u32;
typedef __attribute__((ext_vector_type(8))) short bf16x8;
typedef __attribute__((ext_vector_type(4))) float f32x4;

// ---------- helpers ----------
__device__ __forceinline__ float bf2f(u16 u) {
    union { u32 i; float f; } x; x.i = ((u32)u) << 16; return x.f;
}
__device__ __forceinline__ u16 f2bf(float f) {
    union { float f; u32 i; } x; x.f = f;
    u32 u = x.i;
    u += 0x7FFFu + ((u >> 16) & 1u);   // RNE
    return (u16)(u >> 16);
}
__device__ __forceinline__ float wred(float v) {
    #pragma unroll
    for (int off = 32; off; off >>= 1) v += __shfl_down(v, off);
    return v;
}
__device__ __forceinline__ void gload_lds16(const void* g, void* l) {
    __builtin_amdgcn_global_load_lds(
        (const __attribute__((address_space(1))) u32*)g,
        (__attribute__((address_space(3))) u32*)l,
        16, 0, 0);
}

// ---------- fused prep ----------
// grid = 16384 (x cvt) + 8192 (2 W transposes) + 768 (WgT bf16 [48][4096]) = 25344
__global__ __launch_bounds__(256)
void prep(const float* __restrict__ x, u16* __restrict__ xb,
          const float* __restrict__ Wp, u16* __restrict__ WpT,
          const float* __restrict__ Wf, u16* __restrict__ WfT,
          const float* __restrict__ Wg, u16* __restrict__ WgTb) {
    __shared__ float tile[64][65];
    int b = blockIdx.x;
    int tid = threadIdx.x;
    if (b < 16384) {
        int i = (b * 256 + tid) * 4;
        float4 v = *(const float4*)(x + i);
        ushort4 p;
        p.x = f2bf(v.x); p.y = f2bf(v.y); p.z = f2bf(v.z); p.w = f2bf(v.w);
        *(ushort4*)(xb + i) = p;
    } else if (b < 24576) {
        const float* W = (b < 20480) ? Wp : Wf;
        u16* Wt = (b < 20480) ? WpT : WfT;
        int bid = (b < 20480) ? (b - 16384) : (b - 20480);
        int n0 = (bid & 63) * 64;
        int k0 = (bid >> 6) * 64;
        int tx = tid & 31, ty = tid >> 5;
        #pragma unroll
        for (int i = 0; i < 8; ++i) {
            int kk = ty + i * 8;
            const float* src = W + (size_t)(k0 + kk) * 4096 + n0;
            tile[kk][tx]      = src[tx];
            tile[kk][tx + 32] = src[tx + 32];
        }
        __syncthreads();
        #pragma unroll
        for (int i = 0; i < 8; ++i) {
            int nn = ty + i * 8;
            ushort2 p;
            p.x = f2bf(tile[tx * 2][nn]);
            p.y = f2bf(tile[tx * 2 + 1][nn]);
            *(ushort2*)(Wt + (size_t)(n0 + nn) * 4096 + k0 + tx * 2) = p;
        }
    } else {
        // W_wgen [4096][40] f32 -> WgTb [48][4096] bf16 (rows 40..47 zero)
        int idx = (b - 24576) * 256 + tid;     // 0 .. 196607
        int c = idx >> 12, e = idx & 4095;
        WgTb[idx] = (c < 40) ? f2bf(Wg[(size_t)e * 40 + c]) : (u16)0;
    }
}

// ---------- 256x256 8-phase GEMM, 16x16x32 MFMA, m201-style phase skeleton ----------
// Phase: [reads; stage(1 half-tile); (VM4 at p4/p8); BAR; lgkmcnt(0)+sched_barrier;
//         setprio(1); 16 MFMA; setprio(0); BAR]
// Two barriers/phase: BAR2 certifies all waves' mma done -> their phase reads are
// drained -> distance-1 staging is formally race-free. Explicit lgkmcnt(0) before
// the cluster guarantees a stall-free MFMA burst (setprio holds no lgkm stalls).
// Stage ledger and vmcnt(4)@p4/p8 identical to the round-12-verified dataflow.
// SAFETY INVARIANT: vmcnt is per-wave; every ds_read of a cooperatively staged
// tile is separated from its stage by VM4 + BARRIER.
template <int MODE>
__global__ __launch_bounds__(512, 2)
void gemm256(const u16* __restrict__ A, const u16* __restrict__ Bt,
             const float* __restrict__ bias, const void* __restrict__ res,
             void* __restrict__ outv) {
    const int K = 4096, N = 4096;
    __shared__ u16 smem[65536];   // 128 KB

    const int tid = threadIdx.x;
    const int lane = tid & 63;
    const int w = tid >> 6;
    const int wr = w >> 2, wc = w & 3;
    const int fr = lane & 15;
    const int fk = (lane >> 4) * 8;
    const int cswz = (fr & 7) << 3;

    const int bid = blockIdx.x;
    const int swz = (bid & 7) * (gridDim.x >> 3) + (bid >> 3);
    const int tm = swz >> 4, tn = swz & 15;
    const size_t rowA0 = (size_t)tm * 256;
    const size_t rowB0 = (size_t)tn * 256;

    const int srl = lane >> 3;
    const int scl = ((lane & 7) ^ srl) << 3;

    f32x4 acc[8][4] = {};
    bf16x8 af[8];
    bf16x8 bh0[4];
    bf16x8 bh1[4];

    auto stA = [&](int b, int half, int kt) {
        #pragma unroll
        for (int i = 0; i < 2; ++i) {
            size_t grow = rowA0 + half * 128 + i * 64 + w * 8 + srl;
            gload_lds16(A + grow * K + kt * 64 + scl,
                        &smem[b * 32768 + half * 8192 + i * 4096 + w * 512 + lane * 8]);
        }
    };
    auto stB = [&](int b, int half, int kt) {
        #pragma unroll
        for (int i = 0; i < 2; ++i) {
            size_t grow = rowB0 + half * 128 + i * 64 + w * 8 + srl;
            gload_lds16(Bt + grow * K + kt * 64 + scl,
                        &smem[b * 32768 + 16384 + half * 8192 + i * 4096 + w * 512 + lane * 8]);
        }
    };
    auto ldA = [&](int b, int qm) {
        #pragma unroll
        for (int kk = 0; kk < 2; ++kk)
            #pragma unroll
            for (int m = 0; m < 4; ++m) {
                int base = b * 32768 + (wr * 128 + (qm * 4 + m) * 16 + fr) * 64;
                af[m * 2 + kk] = *(const bf16x8*)&smem[base + ((kk * 32 + fk) ^ cswz)];
            }
    };
    auto ldB = [&](int b, int qn, bf16x8 (&bh)[4]) {
        #pragma unroll
        for (int kk = 0; kk < 2; ++kk)
            #pragma unroll
            for (int n = 0; n < 2; ++n) {
                int base = b * 32768 + 16384 + (wc * 64 + qn * 32 + n * 16 + fr) * 64;
                bh[n * 2 + kk] = *(const bf16x8*)&smem[base + ((kk * 32 + fk) ^ cswz)];
            }
    };
    auto ldAB = [&](int b, int qm, int qn, bf16x8 (&bh)[4]) {
        #pragma unroll
        for (int kk = 0; kk < 2; ++kk) {
            #pragma unroll
            for (int m = 0; m < 4; ++m) {
                int base = b * 32768 + (wr * 128 + (qm * 4 + m) * 16 + fr) * 64;
                af[m * 2 + kk] = *(const bf16x8*)&smem[base + ((kk * 32 + fk) ^ cswz)];
            }
            #pragma unroll
            for (int n = 0; n < 2; ++n) {
                int base = b * 32768 + 16384 + (wc * 64 + qn * 32 + n * 16 + fr) * 64;
                bh[n * 2 + kk] = *(const bf16x8*)&smem[base + ((kk * 32 + fk) ^ cswz)];
            }
        }
    };
    auto mma = [&](int qm, int qn, bf16x8 (&bh)[4]) {
        __builtin_amdgcn_s_setprio(1);
        #pragma unroll
        for (int kk = 0; kk < 2; ++kk)
            #pragma unroll
            for (int m = 0; m < 4; ++m)
                #pragma unroll
                for (int n = 0; n < 2; ++n)
                    acc[qm*4+m][qn*2+n] = __builtin_amdgcn_mfma_f32_16x16x32_bf16(
                        af[m*2+kk], bh[n*2+kk], acc[qm*4+m][qn*2+n], 0, 0, 0);
        __builtin_amdgcn_s_setprio(0);
    };
    #define BAR() __builtin_amdgcn_s_barrier()
    #define VM4() asm volatile("s_waitcnt vmcnt(4)" ::: "memory")
    #define LGKM0() do { asm volatile("s_waitcnt lgkmcnt(0)" ::: "memory"); \
                         __builtin_amdgcn_sched_barrier(0); } while (0)

    // prologue: tile0 fully + B halves of tile1 (12 loads); confirm tile0
    stB(0, 0, 0); stB(0, 1, 0); stA(0, 0, 0); stA(0, 1, 0);
    stB(1, 0, 1); stB(1, 1, 1);
    VM4();
    BAR();

    // 32 uniform iterations, tiles (2i, 2i+1) in (buf0, buf1)
    for (int i = 0; i < 32; ++i) {
        const int t = 2 * i;
        const int kt2 = (t + 2 < 64) ? t + 2 : 63;   // clamped: rewrites identical data
        const int kt3 = (t + 3 < 64) ? t + 3 : 63;
        // p1: tile t, Q(0,0); stage A(t+1)h0
        ldAB(0, 0, 0, bh0);
        stA(1, 0, t + 1);
        BAR(); LGKM0(); mma(0, 0, bh0); BAR();
        // p2: Q(0,1); stage A(t+1)h1
        ldB(0, 1, bh1);
        stA(1, 1, t + 1);
        BAR(); LGKM0(); mma(0, 1, bh1); BAR();
        // p3: Q(1,1); stage B(t+2)h0 (buf0.B last read p2; distance-1 safe under BAR2)
        ldA(0, 1);
        stB(0, 0, kt2);
        BAR(); LGKM0(); mma(1, 1, bh1); BAR();
        // p4: Q(1,0); stage B(t+2)h1; VM4 retires A(t+1); BAR certifies tile t+1
        stB(0, 1, kt2);
        VM4();
        BAR(); LGKM0(); mma(1, 0, bh0); BAR();
        // p5: tile t+1, Q(0,0); stage A(t+2)h0
        ldAB(1, 0, 0, bh0);
        stA(0, 0, kt2);
        BAR(); LGKM0(); mma(0, 0, bh0); BAR();
        // p6: Q(0,1); stage A(t+2)h1
        ldB(1, 1, bh1);
        stA(0, 1, kt2);
        BAR(); LGKM0(); mma(0, 1, bh1); BAR();
        // p7: Q(1,1); stage B(t+3)h0
        ldA(1, 1);
        stB(1, 0, kt3);
        BAR(); LGKM0(); mma(1, 1, bh1); BAR();
        // p8: Q(1,0); stage B(t+3)h1; VM4 retires tile t+2; BAR certifies it
        stB(1, 1, kt3);
        VM4();
        BAR(); LGKM0(); mma(1, 0, bh0); BAR();
    }
    #undef BAR
    #undef VM4
    #undef LGKM0

    const int cc = lane & 15;
    const int cr = (lane >> 4) * 4;
    if (MODE == 2) {
        __builtin_amdgcn_s_barrier();
        #pragma unroll
        for (int m = 0; m < 8; ++m) {
            #pragma unroll
            for (int n = 0; n < 4; ++n) {
                int lc = wc * 64 + n * 16 + cc;
                float bv = bias[rowB0 + lc];
                #pragma unroll
                for (int q = 0; q < 4; ++q) {
                    int lr = wr * 128 + m * 16 + cr + q;
                    int sc = (lc & 7) | (((lc >> 3) ^ (lr & 7)) << 3);
                    smem[lr * 256 + sc] = f2bf(acc[m][n][q] + bv);
                }
            }
        }
        __builtin_amdgcn_s_barrier();
        u16* ob = (u16*)outv;
        #pragma unroll
        for (int it = 0; it < 16; ++it) {
            int idx = it * 512 + tid;
            int lr = idx >> 5;
            int c16 = idx & 31;
            uint4 v = *(uint4*)&smem[lr * 256 + ((c16 ^ (lr & 7)) * 8)];
            *(uint4*)(ob + (rowA0 + lr) * (size_t)N + rowB0 + c16 * 8) = v;
        }
    } else {
        #pragma unroll
        for (int m = 0; m < 8; ++m) {
            #pragma unroll
            for (int n = 0; n < 4; ++n) {
                size_t row = rowA0 + wr * 128 + m * 16 + cr;
                size_t col = rowB0 + wc * 64 + n * 16 + cc;
                float bv = bias[col];
                #pragma unroll
                for (int q = 0; q < 4; ++q) {
                    size_t idx = (row + q) * (size_t)N + col;
                    float v = acc[m][n][q] + bv;
                    if (MODE == 1) v = ((const float*)res)[idx] + fmaxf(v, 0.0f);
                    if (MODE == 3) v = bf2f(((const u16*)res)[idx]) + fmaxf(v, 0.0f);
                    ((float*)outv)[idx] = v;
                }
            }
        }
    }
}

// ---------- fused LayerNorm + MFMA-wgen + softmax + causal dynamic conv ----------
// ylp uses 16B-chunk XOR swizzle (u32 idx ^= row<<2) so wgen's 8-row column
// reads are bank-conflict-free. Applied at LN-write, wgen-read, conv-read.
template <bool HB>
__global__ __launch_bounds__(256)
void ln_conv(const void* __restrict__ hv, const float* __restrict__ g,
             const float* __restrict__ beta, const u16* __restrict__ WgTb,
             const float* __restrict__ bg, u16* __restrict__ conv) {
    __shared__ u32 ylp[8][2048];   // 64 KB, swizzled
    __shared__ float red[8];
    __shared__ float wraw[8][40];
    __shared__ float wsm[8][40];
    __shared__ float pmv[4][2];
    __shared__ float pwg[4][3][8][16];   // 6 KB wgen partials

    int tid = threadIdx.x, lane = tid & 63, wv = tid >> 6;
    size_t row0 = (size_t)blockIdx.x * 8;
    int t0 = (int)(row0 & 511);

    // ---- LN of the 8 main rows -> ylp (swizzled) ----
    for (int r = 0; r < 8; ++r) {
        float vals[16];
        float s = 0.f, ss = 0.f;
        if (HB) {
            const u16* hr = (const u16*)hv + (row0 + r) * 4096;
            #pragma unroll
            for (int i = 0; i < 2; ++i) {
                uint4 u = *(const uint4*)(hr + (size_t)(tid + i * 256) * 8);
                const u16* us = (const u16*)&u;
                #pragma unroll
                for (int j = 0; j < 8; ++j) {
                    float f = bf2f(us[j]);
                    vals[i * 8 + j] = f;
                    s += f; ss += f * f;
                }
            }
        } else {
            const float4* hr = (const float4*)((const float*)hv + (row0 + r) * 4096);
            #pragma unroll
            for (int i = 0; i < 4; ++i) {
                float4 v = hr[tid + i * 256];
                vals[i*4+0] = v.x; vals[i*4+1] = v.y; vals[i*4+2] = v.z; vals[i*4+3] = v.w;
                s  += v.x + v.y + v.z + v.w;
                ss += v.x*v.x + v.y*v.y + v.z*v.z + v.w*v.w;
            }
        }
        s = wred(s); ss = wred(ss);
        if (lane == 0) { red[wv] = s; red[4 + wv] = ss; }
        __syncthreads();
        float S = red[0] + red[1] + red[2] + red[3];
        float SS = red[4] + red[5] + red[6] + red[7];
        float mu = S * (1.0f / 4096.0f);
        float var = SS * (1.0f / 4096.0f) - mu * mu;
        float inv = rsqrtf(var + 1e-5f);
        const int rx = r << 2;               // swizzle XOR for this row
        if (HB) {
            #pragma unroll
            for (int i = 0; i < 2; ++i) {
                int w0 = (i * 1024 + tid * 4) ^ rx;
                u32 words[4];
                #pragma unroll
                for (int k = 0; k < 4; ++k) {
                    int e0 = i * 2048 + tid * 8 + k * 2;
                    float2 gv = *(const float2*)(g + e0);
                    float2 bv = *(const float2*)(beta + e0);
                    float o0 = (vals[i*8 + k*2]     - mu) * inv * gv.x + bv.x;
                    float o1 = (vals[i*8 + k*2 + 1] - mu) * inv * gv.y + bv.y;
                    words[k] = (u32)f2bf(o0) | ((u32)f2bf(o1) << 16);
                }
                uint4 pk; pk.x = words[0]; pk.y = words[1]; pk.z = words[2]; pk.w = words[3];
                *(uint4*)&ylp[r][w0] = pk;
            }
        } else {
            #pragma unroll
            for (int i = 0; i < 4; ++i) {
                int base = tid + i * 256;
                float4 gv = ((const float4*)g)[base];
                float4 bv = ((const float4*)beta)[base];
                float o0 = (vals[i*4+0] - mu) * inv * gv.x + bv.x;
                float o1 = (vals[i*4+1] - mu) * inv * gv.y + bv.y;
                float o2 = (vals[i*4+2] - mu) * inv * gv.z + bv.z;
                float o3 = (vals[i*4+3] - mu) * inv * gv.w + bv.w;
                int w0 = (base * 2) ^ rx;     // bit0 of idx untouched by XOR
                ylp[r][w0]     = (u32)f2bf(o0) | ((u32)f2bf(o1) << 16);
                ylp[r][w0 + 1] = (u32)f2bf(o2) | ((u32)f2bf(o3) << 16);
            }
        }
        __syncthreads();
    }

    // ---- mu/inv of the 4 previous rows ----
    if (t0 > 0) {
        for (int r = 0; r < 4; ++r) {
            size_t row = row0 - 4 + r;
            float s = 0.f, ss = 0.f;
            if (HB) {
                const u16* hr = (const u16*)hv + row * 4096;
                #pragma unroll
                for (int i = 0; i < 2; ++i) {
                    uint4 u = *(const uint4*)(hr + (size_t)(tid + i * 256) * 8);
                    const u16* us = (const u16*)&u;
                    #pragma unroll
                    for (int j = 0; j < 8; ++j) { float f = bf2f(us[j]); s += f; ss += f * f; }
                }
            } else {
                const float4* hr = (const float4*)((const float*)hv + row * 4096);
                #pragma unroll
                for (int i = 0; i < 4; ++i) {
                    float4 v = hr[tid + i * 256];
                    s  += v.x + v.y + v.z + v.w;
                    ss += v.x*v.x + v.y*v.y + v.z*v.z + v.w*v.w;
                }
            }
            s = wred(s); ss = wred(ss);
            if (lane == 0) { red[wv] = s; red[4 + wv] = ss; }
            __syncthreads();
            if (tid == 0) {
                float S = red[0] + red[1] + red[2] + red[3];
                float SS = red[4] + red[5] + red[6] + red[7];
                float mu = S * (1.0f / 4096.0f);
                float var = SS * (1.0f / 4096.0f) - mu * mu;
                pmv[r][0] = mu;
                pmv[r][1] = rsqrtf(var + 1e-5f);
            }
            __syncthreads();
        }
    }

    // ---- wgen via MFMA: wave wv covers k in [wv*1024, wv*1024+1024) ----
    {
        f32x4 wacc[3] = {};
        const int arow = lane & 7;            // A rows 8..15 duplicate 0..7 (ignored)
        const int kofs = (lane >> 4) * 8;
        const int ax = arow << 2;
        #pragma unroll 4
        for (int step = 0; step < 32; ++step) {
            int kg = wv * 1024 + step * 32 + kofs;
            bf16x8 ya = *(const bf16x8*)&ylp[arow][(kg >> 1) ^ ax];
            #pragma unroll
            for (int n = 0; n < 3; ++n) {
                int col = n * 16 + (lane & 15);
                bf16x8 wb = *(const bf16x8*)&WgTb[(size_t)col * 4096 + kg];
                wacc[n] = __builtin_amdgcn_mfma_f32_16x16x32_bf16(ya, wb, wacc[n], 0, 0, 0);
            }
        }
        // C layout: col=lane&15, row=(lane>>4)*4+q; lanes 0..31 hold rows 0..7
        if (lane < 32) {
            int prow = (lane >> 4) * 4;
            int pcol = lane & 15;
            #pragma unroll
            for (int n = 0; n < 3; ++n)
                #pragma unroll
                for (int q = 0; q < 4; ++q)
                    pwg[wv][n][prow + q][pcol] = wacc[n][q];
        }
    }
    __syncthreads();
    for (int t = tid; t < 320; t += 256) {
        int r = t / 40, c = t % 40;
        wraw[r][c] = pwg[0][c >> 4][r][c & 15] + pwg[1][c >> 4][r][c & 15]
                   + pwg[2][c >> 4][r][c & 15] + pwg[3][c >> 4][r][c & 15] + bg[c];
    }
    __syncthreads();

    // ---- softmax -> wsm ----
    if (tid < 64) {
        int r = tid >> 3, hh = tid & 7;
        float e5[5];
        float mx = -1e30f;
        #pragma unroll
        for (int k = 0; k < 5; ++k) mx = fmaxf(mx, wraw[r][hh * 5 + k]);
        float sum = 0.f;
        #pragma unroll
        for (int k = 0; k < 5; ++k) { e5[k] = expf(wraw[r][hh * 5 + k] - mx); sum += e5[k]; }
        float isum = 1.0f / sum;
        #pragma unroll
        for (int k = 0; k < 5; ++k) wsm[r][hh * 5 + k] = e5[k] * isum;
    }
    __syncthreads();

    // ---- conv ----
    for (int half = 0; half < 2; ++half) {
        int d0 = half * 2048 + tid * 8;
        int head = d0 >> 9;
        float yp[4][8];
        #pragma unroll
        for (int r = 0; r < 4; ++r)
            #pragma unroll
            for (int e = 0; e < 8; ++e) yp[r][e] = 0.f;
        if (t0 > 0) {
            float gv[8], bv[8];
            #pragma unroll
            for (int k = 0; k < 2; ++k) {
                float4 gq = *(const float4*)(g + d0 + k * 4);
                float4 bq = *(const float4*)(beta + d0 + k * 4);
                gv[k*4+0]=gq.x; gv[k*4+1]=gq.y; gv[k*4+2]=gq.z; gv[k*4+3]=gq.w;
                bv[k*4+0]=bq.x; bv[k*4+1]=bq.y; bv[k*4+2]=bq.z; bv[k*4+3]=bq.w;
            }
            #pragma unroll
            for (int r = 0; r < 4; ++r) {
                float mu = pmv[r][0], inv = pmv[r][1];
                if (HB) {
                    uint4 u = *(const uint4*)((const u16*)hv + (row0 - 4 + r) * 4096 + d0);
                    const u16* us = (const u16*)&u;
                    #pragma unroll
                    for (int e = 0; e < 8; ++e)
                        yp[r][e] = bf2f(f2bf((bf2f(us[e]) - mu) * inv * gv[e] + bv[e]));
                } else {
                    const float* hr = (const float*)hv + (row0 - 4 + r) * 4096 + d0;
                    #pragma unroll
                    for (int e = 0; e < 8; ++e)
                        yp[r][e] = bf2f(f2bf((hr[e] - mu) * inv * gv[e] + bv[e]));
                }
            }
        }
        #pragma unroll
        for (int ri = 0; ri < 8; ++ri) {
            float a[8] = {0.f,0.f,0.f,0.f,0.f,0.f,0.f,0.f};
            #pragma unroll
            for (int k = 0; k < 5; ++k) {
                int src = ri - 4 + k;
                float w_ = wsm[ri][head * 5 + k];
                if (src >= 0) {
                    uint4 u = *(const uint4*)&ylp[src][(d0 >> 1) ^ (src << 2)];
                    const u16* us = (const u16*)&u;
                    #pragma unroll
                    for (int e = 0; e < 8; ++e) a[e] += w_ * bf2f(us[e]);
                } else {
                    #pragma unroll
                    for (int e = 0; e < 8; ++e) a[e] += w_ * yp[src + 4][e];
                }
            }
            u16 o[8];
            #pragma unroll
            for (int e = 0; e < 8; ++e) o[e] = f2bf(a[e]);
            *(uint4*)(conv + (row0 + ri) * 4096 + d0) = *(uint4*)o;
        }
    }
}

// ---------- launcher ----------
extern "C" void kernel_launch(void* const* d_in, const int* in_sizes, int n_in,
                              void* d_out, int out_size, void* d_ws, size_t ws_size,
                              hipStream_t stream) {
    const float* x      = (const float*)d_in[0];
    const float* W_proj = (const float*)d_in[1];
    const float* b_proj = (const float*)d_in[2];
    const float* ln_g   = (const float*)d_in[3];
    const float* ln_b   = (const float*)d_in[4];
    const float* W_wgen = (const float*)d_in[5];
    const float* b_wgen = (const float*)d_in[6];
    const float* W_ff   = (const float*)d_in[7];
    const float* b_ff   = (const float*)d_in[8];
    float* out = (float*)d_out;

    char* ws = (char*)d_ws;
    u16* xb   = (u16*)(ws);                          // 32 MB, later reused as conv
    u16* WpT  = (u16*)(ws + ((size_t)32 << 20));     // 32 MB
    u16* WfT  = (u16*)(ws + ((size_t)64 << 20));     // 32 MB
    u16* WgTb = (u16*)(ws + ((size_t)96 << 20));     // 384 KB bf16 [48][4096]
    u16* hb   = (u16*)(ws + ((size_t)97 << 20));     // 32 MB (bf16-h path only)
    u16* conv = xb;

    prep<<<25344, 256, 0, stream>>>(x, xb, W_proj, WpT, W_ff, WfT, W_wgen, WgTb);

    if (ws_size >= ((size_t)129 << 20)) {
        gemm256<2><<<256, 512, 0, stream>>>(xb, WpT, b_proj, nullptr, hb);
        ln_conv<true><<<512, 256, 0, stream>>>(hb, ln_g, ln_b, WgTb, b_wgen, conv);
        gemm256<3><<<256, 512, 0, stream>>>(conv, WfT, b_ff, hb, out);
    } else {
        gemm256<0><<<256, 512, 0, stream>>>(xb, WpT, b_proj, nullptr, out);
        ln_conv<false><<<512, 256, 0, stream>>>(out, ln_g, ln_b, WgTb, b_wgen, conv);
        gemm256<1><<<256, 512, 0, stream>>>(conv, WfT, b_ff, out, out);
    }
}

// Round 14
// 312.162 us; speedup vs baseline: 1.0342x; 1.0342x over previous
//
#include <hip/hip_runtime.h>

typedef unsigned short u16;
typedef unsigned int u32;
typedef __attribute__((ext_vector_type(8))) short bf16x8;
typedef __attribute__((ext_vector_type(4))) float f32x4;

// ---------- helpers ----------
__device__ __forceinline__ float bf2f(u16 u) {
    union { u32 i; float f; } x; x.i = ((u32)u) << 16; return x.f;
}
__device__ __forceinline__ u16 f2bf(float f) {
    union { float f; u32 i; } x; x.f = f;
    u32 u = x.i;
    u += 0x7FFFu + ((u >> 16) & 1u);   // RNE
    return (u16)(u >> 16);
}
__device__ __forceinline__ float wred(float v) {
    #pragma unroll
    for (int off = 32; off; off >>= 1) v += __shfl_down(v, off);
    return v;
}
__device__ __forceinline__ void gload_lds16(const void* g, void* l) {
    __builtin_amdgcn_global_load_lds(
        (const __attribute__((address_space(1))) u32*)g,
        (__attribute__((address_space(3))) u32*)l,
        16, 0, 0);
}

// ---------- fused prep ----------
// grid = 16384 (x cvt) + 8192 (2 W transposes) + 768 (WgT bf16 [48][4096]) = 25344
__global__ __launch_bounds__(256)
void prep(const float* __restrict__ x, u16* __restrict__ xb,
          const float* __restrict__ Wp, u16* __restrict__ WpT,
          const float* __restrict__ Wf, u16* __restrict__ WfT,
          const float* __restrict__ Wg, u16* __restrict__ WgTb) {
    __shared__ float tile[64][65];
    int b = blockIdx.x;
    int tid = threadIdx.x;
    if (b < 16384) {
        int i = (b * 256 + tid) * 4;
        float4 v = *(const float4*)(x + i);
        ushort4 p;
        p.x = f2bf(v.x); p.y = f2bf(v.y); p.z = f2bf(v.z); p.w = f2bf(v.w);
        *(ushort4*)(xb + i) = p;
    } else if (b < 24576) {
        const float* W = (b < 20480) ? Wp : Wf;
        u16* Wt = (b < 20480) ? WpT : WfT;
        int bid = (b < 20480) ? (b - 16384) : (b - 20480);
        int n0 = (bid & 63) * 64;
        int k0 = (bid >> 6) * 64;
        int tx = tid & 31, ty = tid >> 5;
        #pragma unroll
        for (int i = 0; i < 8; ++i) {
            int kk = ty + i * 8;
            const float* src = W + (size_t)(k0 + kk) * 4096 + n0;
            tile[kk][tx]      = src[tx];
            tile[kk][tx + 32] = src[tx + 32];
        }
        __syncthreads();
        #pragma unroll
        for (int i = 0; i < 8; ++i) {
            int nn = ty + i * 8;
            ushort2 p;
            p.x = f2bf(tile[tx * 2][nn]);
            p.y = f2bf(tile[tx * 2 + 1][nn]);
            *(ushort2*)(Wt + (size_t)(n0 + nn) * 4096 + k0 + tx * 2) = p;
        }
    } else {
        // W_wgen [4096][40] f32 -> WgTb [48][4096] bf16 (rows 40..47 zero)
        int idx = (b - 24576) * 256 + tid;     // 0 .. 196607
        int c = idx >> 12, e = idx & 4095;
        WgTb[idx] = (c < 40) ? f2bf(Wg[(size_t)e * 40 + c]) : (u16)0;
    }
}

// ---------- 256x256 8-phase GEMM, 16x16x32 MFMA (round-12-verified schedule) ----------
// MODE 0: f32 out = acc + bias          MODE 2: bf16 out = acc + bias (LDS-coalesced)
// MODE 1: f32 out = f32 res + relu(.)   MODE 3: f32 out = bf16 res + relu(.)
// ONE barrier per phase; ONE half-tile staged per phase. vmcnt(4) at p4/p8 only.
// SAFETY INVARIANT: vmcnt is per-wave; every ds_read of a cooperatively staged
// tile is separated from its stage by VM4 + BARRIER.
template <int MODE>
__global__ __launch_bounds__(512, 2)
void gemm256(const u16* __restrict__ A, const u16* __restrict__ Bt,
             const float* __restrict__ bias, const void* __restrict__ res,
             void* __restrict__ outv) {
    const int K = 4096, N = 4096;
    __shared__ u16 smem[65536];   // 128 KB

    const int tid = threadIdx.x;
    const int lane = tid & 63;
    const int w = tid >> 6;
    const int wr = w >> 2, wc = w & 3;
    const int fr = lane & 15;
    const int fk = (lane >> 4) * 8;
    const int cswz = (fr & 7) << 3;

    const int bid = blockIdx.x;
    const int swz = (bid & 7) * (gridDim.x >> 3) + (bid >> 3);
    const int tm = swz >> 4, tn = swz & 15;
    const size_t rowA0 = (size_t)tm * 256;
    const size_t rowB0 = (size_t)tn * 256;

    const int srl = lane >> 3;
    const int scl = ((lane & 7) ^ srl) << 3;

    f32x4 acc[8][4] = {};
    bf16x8 af[8];
    bf16x8 bh0[4];
    bf16x8 bh1[4];

    auto stA = [&](int b, int half, int kt) {
        #pragma unroll
        for (int i = 0; i < 2; ++i) {
            size_t grow = rowA0 + half * 128 + i * 64 + w * 8 + srl;
            gload_lds16(A + grow * K + kt * 64 + scl,
                        &smem[b * 32768 + half * 8192 + i * 4096 + w * 512 + lane * 8]);
        }
    };
    auto stB = [&](int b, int half, int kt) {
        #pragma unroll
        for (int i = 0; i < 2; ++i) {
            size_t grow = rowB0 + half * 128 + i * 64 + w * 8 + srl;
            gload_lds16(Bt + grow * K + kt * 64 + scl,
                        &smem[b * 32768 + 16384 + half * 8192 + i * 4096 + w * 512 + lane * 8]);
        }
    };
    auto ldA = [&](int b, int qm) {
        #pragma unroll
        for (int kk = 0; kk < 2; ++kk)
            #pragma unroll
            for (int m = 0; m < 4; ++m) {
                int base = b * 32768 + (wr * 128 + (qm * 4 + m) * 16 + fr) * 64;
                af[m * 2 + kk] = *(const bf16x8*)&smem[base + ((kk * 32 + fk) ^ cswz)];
            }
    };
    auto ldB = [&](int b, int qn, bf16x8 (&bh)[4]) {
        #pragma unroll
        for (int kk = 0; kk < 2; ++kk)
            #pragma unroll
            for (int n = 0; n < 2; ++n) {
                int base = b * 32768 + 16384 + (wc * 64 + qn * 32 + n * 16 + fr) * 64;
                bh[n * 2 + kk] = *(const bf16x8*)&smem[base + ((kk * 32 + fk) ^ cswz)];
            }
    };
    auto ldAB = [&](int b, int qm, int qn, bf16x8 (&bh)[4]) {
        #pragma unroll
        for (int kk = 0; kk < 2; ++kk) {
            #pragma unroll
            for (int m = 0; m < 4; ++m) {
                int base = b * 32768 + (wr * 128 + (qm * 4 + m) * 16 + fr) * 64;
                af[m * 2 + kk] = *(const bf16x8*)&smem[base + ((kk * 32 + fk) ^ cswz)];
            }
            #pragma unroll
            for (int n = 0; n < 2; ++n) {
                int base = b * 32768 + 16384 + (wc * 64 + qn * 32 + n * 16 + fr) * 64;
                bh[n * 2 + kk] = *(const bf16x8*)&smem[base + ((kk * 32 + fk) ^ cswz)];
            }
        }
    };
    auto mma = [&](int qm, int qn, bf16x8 (&bh)[4]) {
        __builtin_amdgcn_s_setprio(1);
        #pragma unroll
        for (int kk = 0; kk < 2; ++kk)
            #pragma unroll
            for (int m = 0; m < 4; ++m)
                #pragma unroll
                for (int n = 0; n < 2; ++n)
                    acc[qm*4+m][qn*2+n] = __builtin_amdgcn_mfma_f32_16x16x32_bf16(
                        af[m*2+kk], bh[n*2+kk], acc[qm*4+m][qn*2+n], 0, 0, 0);
        __builtin_amdgcn_s_setprio(0);
    };
    #define BAR() __builtin_amdgcn_s_barrier()
    #define VM4() asm volatile("s_waitcnt vmcnt(4)" ::: "memory")

    stB(0, 0, 0); stB(0, 1, 0); stA(0, 0, 0); stA(0, 1, 0);
    stB(1, 0, 1); stB(1, 1, 1);
    VM4();
    BAR();

    for (int i = 0; i < 32; ++i) {
        const int t = 2 * i;
        const int kt2 = (t + 2 < 64) ? t + 2 : 63;
        const int kt3 = (t + 3 < 64) ? t + 3 : 63;
        ldAB(0, 0, 0, bh0);
        stA(1, 0, t + 1);
        BAR(); mma(0, 0, bh0);
        ldB(0, 1, bh1);
        stA(1, 1, t + 1);
        BAR(); mma(0, 1, bh1);
        ldA(0, 1);
        stB(0, 0, kt2);
        BAR(); mma(1, 1, bh1);
        stB(0, 1, kt2);
        VM4();
        BAR(); mma(1, 0, bh0);
        ldAB(1, 0, 0, bh0);
        stA(0, 0, kt2);
        BAR(); mma(0, 0, bh0);
        ldB(1, 1, bh1);
        stA(0, 1, kt2);
        BAR(); mma(0, 1, bh1);
        ldA(1, 1);
        stB(1, 0, kt3);
        BAR(); mma(1, 1, bh1);
        stB(1, 1, kt3);
        VM4();
        BAR(); mma(1, 0, bh0);
    }
    #undef BAR
    #undef VM4

    const int cc = lane & 15;
    const int cr = (lane >> 4) * 4;
    if (MODE == 2) {
        __builtin_amdgcn_s_barrier();
        #pragma unroll
        for (int m = 0; m < 8; ++m) {
            #pragma unroll
            for (int n = 0; n < 4; ++n) {
                int lc = wc * 64 + n * 16 + cc;
                float bv = bias[rowB0 + lc];
                #pragma unroll
                for (int q = 0; q < 4; ++q) {
                    int lr = wr * 128 + m * 16 + cr + q;
                    int sc = (lc & 7) | (((lc >> 3) ^ (lr & 7)) << 3);
                    smem[lr * 256 + sc] = f2bf(acc[m][n][q] + bv);
                }
            }
        }
        __builtin_amdgcn_s_barrier();
        u16* ob = (u16*)outv;
        #pragma unroll
        for (int it = 0; it < 16; ++it) {
            int idx = it * 512 + tid;
            int lr = idx >> 5;
            int c16 = idx & 31;
            uint4 v = *(uint4*)&smem[lr * 256 + ((c16 ^ (lr & 7)) * 8)];
            *(uint4*)(ob + (rowA0 + lr) * (size_t)N + rowB0 + c16 * 8) = v;
        }
    } else {
        #pragma unroll
        for (int m = 0; m < 8; ++m) {
            #pragma unroll
            for (int n = 0; n < 4; ++n) {
                size_t row = rowA0 + wr * 128 + m * 16 + cr;
                size_t col = rowB0 + wc * 64 + n * 16 + cc;
                float bv = bias[col];
                #pragma unroll
                for (int q = 0; q < 4; ++q) {
                    size_t idx = (row + q) * (size_t)N + col;
                    float v = acc[m][n][q] + bv;
                    if (MODE == 1) v = ((const float*)res)[idx] + fmaxf(v, 0.0f);
                    if (MODE == 3) v = bf2f(((const u16*)res)[idx]) + fmaxf(v, 0.0f);
                    ((float*)outv)[idx] = v;
                }
            }
        }
    }
}

// ---------- fused LayerNorm + MFMA-wgen + softmax + causal dynamic conv ----------
// ylp uses 16B-chunk XOR swizzle (u32 idx ^= row<<2) so wgen's 8-row column
// reads are bank-conflict-free. Applied at LN-write, wgen-read, conv-read.
template <bool HB>
__global__ __launch_bounds__(256)
void ln_conv(const void* __restrict__ hv, const float* __restrict__ g,
             const float* __restrict__ beta, const u16* __restrict__ WgTb,
             const float* __restrict__ bg, u16* __restrict__ conv) {
    __shared__ u32 ylp[8][2048];   // 64 KB, swizzled
    __shared__ float red[8];
    __shared__ float wraw[8][40];
    __shared__ float wsm[8][40];
    __shared__ float pmv[4][2];
    __shared__ float pwg[4][3][8][16];   // 6 KB wgen partials

    int tid = threadIdx.x, lane = tid & 63, wv = tid >> 6;
    size_t row0 = (size_t)blockIdx.x * 8;
    int t0 = (int)(row0 & 511);

    // ---- LN of the 8 main rows -> ylp (swizzled) ----
    for (int r = 0; r < 8; ++r) {
        float vals[16];
        float s = 0.f, ss = 0.f;
        if (HB) {
            const u16* hr = (const u16*)hv + (row0 + r) * 4096;
            #pragma unroll
            for (int i = 0; i < 2; ++i) {
                uint4 u = *(const uint4*)(hr + (size_t)(tid + i * 256) * 8);
                const u16* us = (const u16*)&u;
                #pragma unroll
                for (int j = 0; j < 8; ++j) {
                    float f = bf2f(us[j]);
                    vals[i * 8 + j] = f;
                    s += f; ss += f * f;
                }
            }
        } else {
            const float4* hr = (const float4*)((const float*)hv + (row0 + r) * 4096);
            #pragma unroll
            for (int i = 0; i < 4; ++i) {
                float4 v = hr[tid + i * 256];
                vals[i*4+0] = v.x; vals[i*4+1] = v.y; vals[i*4+2] = v.z; vals[i*4+3] = v.w;
                s  += v.x + v.y + v.z + v.w;
                ss += v.x*v.x + v.y*v.y + v.z*v.z + v.w*v.w;
            }
        }
        s = wred(s); ss = wred(ss);
        if (lane == 0) { red[wv] = s; red[4 + wv] = ss; }
        __syncthreads();
        float S = red[0] + red[1] + red[2] + red[3];
        float SS = red[4] + red[5] + red[6] + red[7];
        float mu = S * (1.0f / 4096.0f);
        float var = SS * (1.0f / 4096.0f) - mu * mu;
        float inv = rsqrtf(var + 1e-5f);
        const int rx = r << 2;               // swizzle XOR for this row
        if (HB) {
            #pragma unroll
            for (int i = 0; i < 2; ++i) {
                int w0 = (i * 1024 + tid * 4) ^ rx;
                u32 words[4];
                #pragma unroll
                for (int k = 0; k < 4; ++k) {
                    int e0 = i * 2048 + tid * 8 + k * 2;
                    float2 gv = *(const float2*)(g + e0);
                    float2 bv = *(const float2*)(beta + e0);
                    float o0 = (vals[i*8 + k*2]     - mu) * inv * gv.x + bv.x;
                    float o1 = (vals[i*8 + k*2 + 1] - mu) * inv * gv.y + bv.y;
                    words[k] = (u32)f2bf(o0) | ((u32)f2bf(o1) << 16);
                }
                uint4 pk; pk.x = words[0]; pk.y = words[1]; pk.z = words[2]; pk.w = words[3];
                *(uint4*)&ylp[r][w0] = pk;
            }
        } else {
            #pragma unroll
            for (int i = 0; i < 4; ++i) {
                int base = tid + i * 256;
                float4 gv = ((const float4*)g)[base];
                float4 bv = ((const float4*)beta)[base];
                float o0 = (vals[i*4+0] - mu) * inv * gv.x + bv.x;
                float o1 = (vals[i*4+1] - mu) * inv * gv.y + bv.y;
                float o2 = (vals[i*4+2] - mu) * inv * gv.z + bv.z;
                float o3 = (vals[i*4+3] - mu) * inv * gv.w + bv.w;
                int w0 = (base * 2) ^ rx;     // bit0 of idx untouched by XOR
                ylp[r][w0]     = (u32)f2bf(o0) | ((u32)f2bf(o1) << 16);
                ylp[r][w0 + 1] = (u32)f2bf(o2) | ((u32)f2bf(o3) << 16);
            }
        }
        __syncthreads();
    }

    // ---- mu/inv of the 4 previous rows ----
    if (t0 > 0) {
        for (int r = 0; r < 4; ++r) {
            size_t row = row0 - 4 + r;
            float s = 0.f, ss = 0.f;
            if (HB) {
                const u16* hr = (const u16*)hv + row * 4096;
                #pragma unroll
                for (int i = 0; i < 2; ++i) {
                    uint4 u = *(const uint4*)(hr + (size_t)(tid + i * 256) * 8);
                    const u16* us = (const u16*)&u;
                    #pragma unroll
                    for (int j = 0; j < 8; ++j) { float f = bf2f(us[j]); s += f; ss += f * f; }
                }
            } else {
                const float4* hr = (const float4*)((const float*)hv + row * 4096);
                #pragma unroll
                for (int i = 0; i < 4; ++i) {
                    float4 v = hr[tid + i * 256];
                    s  += v.x + v.y + v.z + v.w;
                    ss += v.x*v.x + v.y*v.y + v.z*v.z + v.w*v.w;
                }
            }
            s = wred(s); ss = wred(ss);
            if (lane == 0) { red[wv] = s; red[4 + wv] = ss; }
            __syncthreads();
            if (tid == 0) {
                float S = red[0] + red[1] + red[2] + red[3];
                float SS = red[4] + red[5] + red[6] + red[7];
                float mu = S * (1.0f / 4096.0f);
                float var = SS * (1.0f / 4096.0f) - mu * mu;
                pmv[r][0] = mu;
                pmv[r][1] = rsqrtf(var + 1e-5f);
            }
            __syncthreads();
        }
    }

    // ---- wgen via MFMA: wave wv covers k in [wv*1024, wv*1024+1024) ----
    {
        f32x4 wacc[3] = {};
        const int arow = lane & 7;            // A rows 8..15 duplicate 0..7 (ignored)
        const int kofs = (lane >> 4) * 8;
        const int ax = arow << 2;
        #pragma unroll 4
        for (int step = 0; step < 32; ++step) {
            int kg = wv * 1024 + step * 32 + kofs;
            bf16x8 ya = *(const bf16x8*)&ylp[arow][(kg >> 1) ^ ax];
            #pragma unroll
            for (int n = 0; n < 3; ++n) {
                int col = n * 16 + (lane & 15);
                bf16x8 wb = *(const bf16x8*)&WgTb[(size_t)col * 4096 + kg];
                wacc[n] = __builtin_amdgcn_mfma_f32_16x16x32_bf16(ya, wb, wacc[n], 0, 0, 0);
            }
        }
        // C layout: col=lane&15, row=(lane>>4)*4+q; lanes 0..31 hold rows 0..7
        if (lane < 32) {
            int prow = (lane >> 4) * 4;
            int pcol = lane & 15;
            #pragma unroll
            for (int n = 0; n < 3; ++n)
                #pragma unroll
                for (int q = 0; q < 4; ++q)
                    pwg[wv][n][prow + q][pcol] = wacc[n][q];
        }
    }
    __syncthreads();
    for (int t = tid; t < 320; t += 256) {
        int r = t / 40, c = t % 40;
        wraw[r][c] = pwg[0][c >> 4][r][c & 15] + pwg[1][c >> 4][r][c & 15]
                   + pwg[2][c >> 4][r][c & 15] + pwg[3][c >> 4][r][c & 15] + bg[c];
    }
    __syncthreads();

    // ---- softmax -> wsm ----
    if (tid < 64) {
        int r = tid >> 3, hh = tid & 7;
        float e5[5];
        float mx = -1e30f;
        #pragma unroll
        for (int k = 0; k < 5; ++k) mx = fmaxf(mx, wraw[r][hh * 5 + k]);
        float sum = 0.f;
        #pragma unroll
        for (int k = 0; k < 5; ++k) { e5[k] = expf(wraw[r][hh * 5 + k] - mx); sum += e5[k]; }
        float isum = 1.0f / sum;
        #pragma unroll
        for (int k = 0; k < 5; ++k) wsm[r][hh * 5 + k] = e5[k] * isum;
    }
    __syncthreads();

    // ---- conv ----
    for (int half = 0; half < 2; ++half) {
        int d0 = half * 2048 + tid * 8;
        int head = d0 >> 9;
        float yp[4][8];
        #pragma unroll
        for (int r = 0; r < 4; ++r)
            #pragma unroll
            for (int e = 0; e < 8; ++e) yp[r][e] = 0.f;
        if (t0 > 0) {
            float gv[8], bv[8];
            #pragma unroll
            for (int k = 0; k < 2; ++k) {
                float4 gq = *(const float4*)(g + d0 + k * 4);
                float4 bq = *(const float4*)(beta + d0 + k * 4);
                gv[k*4+0]=gq.x; gv[k*4+1]=gq.y; gv[k*4+2]=gq.z; gv[k*4+3]=gq.w;
                bv[k*4+0]=bq.x; bv[k*4+1]=bq.y; bv[k*4+2]=bq.z; bv[k*4+3]=bq.w;
            }
            #pragma unroll
            for (int r = 0; r < 4; ++r) {
                float mu = pmv[r][0], inv = pmv[r][1];
                if (HB) {
                    uint4 u = *(const uint4*)((const u16*)hv + (row0 - 4 + r) * 4096 + d0);
                    const u16* us = (const u16*)&u;
                    #pragma unroll
                    for (int e = 0; e < 8; ++e)
                        yp[r][e] = bf2f(f2bf((bf2f(us[e]) - mu) * inv * gv[e] + bv[e]));
                } else {
                    const float* hr = (const float*)hv + (row0 - 4 + r) * 4096 + d0;
                    #pragma unroll
                    for (int e = 0; e < 8; ++e)
                        yp[r][e] = bf2f(f2bf((hr[e] - mu) * inv * gv[e] + bv[e]));
                }
            }
        }
        #pragma unroll
        for (int ri = 0; ri < 8; ++ri) {
            float a[8] = {0.f,0.f,0.f,0.f,0.f,0.f,0.f,0.f};
            #pragma unroll
            for (int k = 0; k < 5; ++k) {
                int src = ri - 4 + k;
                float w_ = wsm[ri][head * 5 + k];
                if (src >= 0) {
                    uint4 u = *(const uint4*)&ylp[src][(d0 >> 1) ^ (src << 2)];
                    const u16* us = (const u16*)&u;
                    #pragma unroll
                    for (int e = 0; e < 8; ++e) a[e] += w_ * bf2f(us[e]);
                } else {
                    #pragma unroll
                    for (int e = 0; e < 8; ++e) a[e] += w_ * yp[src + 4][e];
                }
            }
            u16 o[8];
            #pragma unroll
            for (int e = 0; e < 8; ++e) o[e] = f2bf(a[e]);
            *(uint4*)(conv + (row0 + ri) * 4096 + d0) = *(uint4*)o;
        }
    }
}

// ---------- launcher ----------
extern "C" void kernel_launch(void* const* d_in, const int* in_sizes, int n_in,
                              void* d_out, int out_size, void* d_ws, size_t ws_size,
                              hipStream_t stream) {
    const float* x      = (const float*)d_in[0];
    const float* W_proj = (const float*)d_in[1];
    const float* b_proj = (const float*)d_in[2];
    const float* ln_g   = (const float*)d_in[3];
    const float* ln_b   = (const float*)d_in[4];
    const float* W_wgen = (const float*)d_in[5];
    const float* b_wgen = (const float*)d_in[6];
    const float* W_ff   = (const float*)d_in[7];
    const float* b_ff   = (const float*)d_in[8];
    float* out = (float*)d_out;

    char* ws = (char*)d_ws;
    u16* xb   = (u16*)(ws);                          // 32 MB, later reused as conv
    u16* WpT  = (u16*)(ws + ((size_t)32 << 20));     // 32 MB
    u16* WfT  = (u16*)(ws + ((size_t)64 << 20));     // 32 MB
    u16* WgTb = (u16*)(ws + ((size_t)96 << 20));     // 384 KB bf16 [48][4096]
    u16* hb   = (u16*)(ws + ((size_t)97 << 20));     // 32 MB (bf16-h path only)
    u16* conv = xb;

    prep<<<25344, 256, 0, stream>>>(x, xb, W_proj, WpT, W_ff, WfT, W_wgen, WgTb);

    if (ws_size >= ((size_t)129 << 20)) {
        gemm256<2><<<256, 512, 0, stream>>>(xb, WpT, b_proj, nullptr, hb);
        ln_conv<true><<<512, 256, 0, stream>>>(hb, ln_g, ln_b, WgTb, b_wgen, conv);
        gemm256<3><<<256, 512, 0, stream>>>(conv, WfT, b_ff, hb, out);
    } else {
        gemm256<0><<<256, 512, 0, stream>>>(xb, WpT, b_proj, nullptr, out);
        ln_conv<false><<<512, 256, 0, stream>>>(out, ln_g, ln_b, WgTb, b_wgen, conv);
        gemm256<1><<<256, 512, 0, stream>>>(conv, WfT, b_ff, out, out);
    }
}